// Round 12
// baseline (14060.213 us; speedup 1.0000x reference)
//
#include <hip/hip_runtime.h>

#define NTHR 1024
#define NB   16
#define NOSC 50
#define NPER 40
#define KTOT 2000
#define KPAD 2048
#define NSTEP 700
#define BATCH 4096
#define B1STR 36
#define OS_STR 36
#define HALF_PI 1.57079632679489662f
#define ACT_OFF ((size_t)NSTEP * BATCH * 4)

typedef _Float16 v8h __attribute__((ext_vector_type(8)));
typedef _Float16 h2_t __attribute__((ext_vector_type(2)));
typedef float v4f __attribute__((ext_vector_type(4)));

__device__ _Float16 g_w4[32 * KPAD];    // fc4_w in f16, zero-padded K 2000->2048

__device__ __forceinline__ float fdot2f(float a_bits, float b_bits, float acc) {
    h2_t a = __builtin_bit_cast(h2_t, a_bits);
    h2_t b = __builtin_bit_cast(h2_t, b_bits);
#if __has_builtin(__builtin_amdgcn_fdot2)
    return __builtin_amdgcn_fdot2(a, b, acc, false);
#else
    return fmaf((float)a[0], (float)b[0], fmaf((float)a[1], (float)b[1], acc));
#endif
}

__device__ __forceinline__ float dot4(float4 a, float4 b, float acc) {
    acc = fmaf(a.x, b.x, acc);
    acc = fmaf(a.y, b.y, acc);
    acc = fmaf(a.z, b.z, acc);
    acc = fmaf(a.w, b.w, acc);
    return acc;
}

__device__ __forceinline__ float pkrtz(float a, float b) {
    auto q = __builtin_amdgcn_cvt_pkrtz(a, b);
    return __builtin_bit_cast(float, q);
}

// pack 2 f32 -> 2 f16 with round-to-nearest (matches old (_Float16) LDS staging)
__device__ __forceinline__ float cvt2rtn(float a, float b) {
    h2_t u; u[0] = (_Float16)a; u[1] = (_Float16)b;
    return __builtin_bit_cast(float, u);
}

__global__ void prep_f16(const float* __restrict__ fc4_w) {
    int tid = blockIdx.x * blockDim.x + threadIdx.x;   // 65536 total
    int j = tid >> 11, k = tid & 2047;
    g_w4[j * KPAD + k] = (k < KTOT) ? (_Float16)fc4_w[j * KTOT + k] : (_Float16)0.f;
}

// act layout: element (b, k): oct = k>>3, j = k&7, slot = (b ^ oct) & 15
//   f16 idx = oct*128 + slot*8 + j
// r11 post-mortem: vmcnt-drain removal null -> kernel is LDS-ISSUE-bound
// (~390 wave-ops/step). This round deletes wave-ops:
//  - GEMM concentrated in 4 waves x 16 K-steps (32 v8h weights/wave, AGPR-
//    parked): part 16->4 partials => part-writes 32->8 wave-ops, R reads
//    16->4 per thread. K association order preserved -> bit-identical.
//  - deriv on t in [256,1008): 750 threads, o=i/15 (b=15 second task reuses
//    the same dec regs); fc5/limb on t>=1008 (oct>=252, outside phaseA).
// 2 barriers/step:
//   P1: MFMA(t<256) | deriv(256<=t<1006) | fc5/limb/store(s-1) on t>=1008
//   P2: R4(t<512); phaseA(s+1) on all
__global__ __launch_bounds__(NTHR)
void net_main(const float* __restrict__ x,
              const float* __restrict__ fc1_w, const float* __restrict__ fc1_b,
              const float* __restrict__ fc2_w, const float* __restrict__ fc2_b,
              const float* __restrict__ fc3_w, const float* __restrict__ fc3_b,
              const float* __restrict__ fcd_w, const float* __restrict__ fcd_b,
              const float* __restrict__ enc,   const float* __restrict__ osc_bias,
              const float* __restrict__ dec,
              const float* __restrict__ fc4_b,
              const float* __restrict__ fc5_w, const float* __restrict__ fc5_b,
              float* __restrict__ out)
{
    __shared__ __align__(16) _Float16 act_sh[256 * 128];  // 64 KB, frag-major
    __shared__ __align__(16) float part[4 * 2 * 256];     // 8 KB, MFMA partials (swizzled)
    __shared__ __align__(16) float os_sh[NOSC * OS_STR];  // 7.2 KB [o][b*2+d], padded stride
    __shared__ __align__(16) float b1s[NB * B1STR];
    __shared__ __align__(16) float dir[NB * 2];

    const int t    = threadIdx.x;
    const int lane = t & 63;
    const int wv   = t >> 6;            // 0..15
    const int b0   = blockIdx.x * NB;

    float* h  = (float*)act_sh;         // [NB][128] f32 temp (pre-loop only)
    float* h2 = (float*)act_sh + NB * 128;

    // ---------- precompute: fc1 ----------
    #pragma unroll
    for (int ii = 0; ii < 2; ++ii) {
        int task = t + ii * NTHR;       // 2048 tasks
        int b = task >> 7, i = task & 127;
        float x0 = x[(b0 + b) * 2 + 0];
        float x1 = x[(b0 + b) * 2 + 1];
        float v = fmaf(x0, fc1_w[2 * i], fmaf(x1, fc1_w[2 * i + 1], fc1_b[i]));
        h[b * 128 + i] = fmaxf(v, 0.f);
    }
    __syncthreads();
    // ---------- precompute: fc2 -> h2, fcd -> dir ----------
    #pragma unroll
    for (int ii = 0; ii < 2; ++ii) {
        int task = t + ii * NTHR;
        int b = task >> 7, i = task & 127;
        float acc = fc2_b[i];
        #pragma unroll 4
        for (int k = 0; k < 128; k += 4)
            acc = dot4(*(const float4*)&fc2_w[i * 128 + k],
                       *(const float4*)&h[b * 128 + k], acc);
        h2[b * 128 + i] = fmaxf(acc, 0.f);
    }
    if (t < NB * 2) {
        int b = t >> 1, j = t & 1;
        float acc = fcd_b[j];
        #pragma unroll 4
        for (int k = 0; k < 128; k += 4)
            acc = dot4(*(const float4*)&fcd_w[j * 128 + k],
                       *(const float4*)&h[b * 128 + k], acc);
        dir[b * 2 + j] = acc;
    }
    __syncthreads();
    // ---------- precompute: fc3 -> os_sh ----------
    #pragma unroll
    for (int ii = 0; ii < 2; ++ii) {
        int task = t + ii * NTHR;
        if (task < NOSC * NB * 2) {     // 1600 tasks
            int o = task >> 5, r = task & 31, b = r >> 1;
            int row = o * 2 + (r & 1);
            float acc = fc3_b[row];
            #pragma unroll 4
            for (int k = 0; k < 128; k += 4)
                acc = dot4(*(const float4*)&fc3_w[row * 128 + k],
                           *(const float4*)&h2[b * 128 + k], acc);
            os_sh[o * OS_STR + r] = acc;
        }
    }
    // ---------- enc/bias -> per-thread registers (oct fixed per thread) ----------
    const int my_oct = t >> 2;          // 0..255; threads with oct>=250 idle in phaseA
    float4 e0 = {0,0,0,0}, e1 = {0,0,0,0}, e2 = {0,0,0,0}, e3 = {0,0,0,0};
    float4 bi0 = {0,0,0,0}, bi1 = {0,0,0,0};
    int my_o = 0;
    if (my_oct < 250) {
        const float4* ep = (const float4*)&enc[my_oct * 16];
        e0 = ep[0]; e1 = ep[1]; e2 = ep[2]; e3 = ep[3];
        const float4* bp = (const float4*)&osc_bias[my_oct * 8];
        bi0 = bp[0]; bi1 = bp[1];
        my_o = my_oct / 5;
    }
    // ---------- dec -> per-thread registers (deriv threads t in [256,1006)) ----------
    const int di = t - 256;             // deriv index
    int d_o = 0, d_r = 0;
    float4 dd0[5], dd1[5];
    if (di >= 0 && di < 750) {
        d_o = di / 15;
        d_r = di - d_o * 15;
        const float* d0p = &dec[(d_o * 2 + 0) * 40];
        const float* d1p = &dec[(d_o * 2 + 1) * 40];
        #pragma unroll
        for (int c = 0; c < 5; ++c) {
            dd0[c].x = cvt2rtn(d0p[c*8+0], d0p[c*8+1]);
            dd0[c].y = cvt2rtn(d0p[c*8+2], d0p[c*8+3]);
            dd0[c].z = cvt2rtn(d0p[c*8+4], d0p[c*8+5]);
            dd0[c].w = cvt2rtn(d0p[c*8+6], d0p[c*8+7]);
            dd1[c].x = cvt2rtn(d1p[c*8+0], d1p[c*8+1]);
            dd1[c].y = cvt2rtn(d1p[c*8+2], d1p[c*8+3]);
            dd1[c].z = cvt2rtn(d1p[c*8+4], d1p[c*8+5]);
            dd1[c].w = cvt2rtn(d1p[c*8+6], d1p[c*8+7]);
        }
    }
    // ---------- limb init (threads 1008..1023 own the ODE + stores) ----------
    float theta = 0.f, omega = 0.f, l1 = 0.f, l2 = 0.f, bs0 = 0.f, bs1 = 0.f;
    const int cb = t - 1008;            // 0..15 on tail of wave 15
    if (cb >= 0 && cb < NB) {
        theta = x[(b0 + cb) * 2 + 0];
        l1 = fmaf(-0.02f, theta, 0.1f);
        l2 = fmaf( 0.02f, theta, 0.1f);
    }
    __syncthreads();
    if (cb >= 0 && cb < NB) {
        bs0 = dir[cb * 2 + 0] + fc5_b[0];
        bs1 = dir[cb * 2 + 1] + fc5_b[1];
    }
    // zero act padding (octets 250..255 -> f16 idx [32000, 32768))
    if (t < 768) act_sh[32000 + t] = (_Float16)0.f;

    // ---------- MFMA wave setup: 4 waves x 16 K-steps, weights in regs/AGPRs ----------
    const int n_col = lane & 15, quad = lane >> 4;
    const int lidx  = lane ^ (quad << 2);           // part write swizzle
    const int a_base = wv * 8192 + quad * 128;      // f16 idx; +ks*512 + ax[ks&3]
    int ax[4];
    #pragma unroll
    for (int m = 0; m < 4; ++m)
        ax[m] = (n_col ^ (m * 4 + quad)) * 8;
    v8h wr[32];                         // B-fragments for 32 MFMAs (AGPR-parked)
    if (t < 256) {
        const _Float16* wp = &g_w4[n_col * KPAD + wv * 512 + quad * 8];
        #pragma unroll
        for (int ks = 0; ks < 16; ++ks) {
            wr[ks]      = *(const v8h*)&wp[ks * 32];
            wr[16 + ks] = *(const v8h*)&wp[16 * KPAD + ks * 32];
        }
    }

    // ---------- phase A: act = relu(enc . os + bias), enc/bias in REGISTERS ----------
    // thread covers b = (t&3)*4 + ii, ii=0..3 -> slot bijective per 16-lane group
    auto phaseA = [&]() {
        if (my_oct < 250) {
            const int i4 = (t & 3) << 2;
            float4 osA = *(const float4*)&os_sh[my_o * OS_STR + i4 * 2];      // b=i4+0,1
            float4 osB = *(const float4*)&os_sh[my_o * OS_STR + i4 * 2 + 4];  // b=i4+2,3
            #pragma unroll
            for (int ii = 0; ii < 4; ++ii) {
                int b = i4 + ii;
                float osx = (ii == 0) ? osA.x : (ii == 1) ? osA.z : (ii == 2) ? osB.x : osB.z;
                float osy = (ii == 0) ? osA.y : (ii == 1) ? osA.w : (ii == 2) ? osB.y : osB.w;
                float r0 = fmaxf(fmaf(e0.x, osx, fmaf(e0.y, osy, bi0.x)), 0.f);
                float r1 = fmaxf(fmaf(e0.z, osx, fmaf(e0.w, osy, bi0.y)), 0.f);
                float r2 = fmaxf(fmaf(e1.x, osx, fmaf(e1.y, osy, bi0.z)), 0.f);
                float r3 = fmaxf(fmaf(e1.z, osx, fmaf(e1.w, osy, bi0.w)), 0.f);
                float r4 = fmaxf(fmaf(e2.x, osx, fmaf(e2.y, osy, bi1.x)), 0.f);
                float r5 = fmaxf(fmaf(e2.z, osx, fmaf(e2.w, osy, bi1.y)), 0.f);
                float r6 = fmaxf(fmaf(e3.x, osx, fmaf(e3.y, osy, bi1.z)), 0.f);
                float r7 = fmaxf(fmaf(e3.z, osx, fmaf(e3.w, osy, bi1.w)), 0.f);
                float4 pk;
                pk.x = pkrtz(r0, r1);
                pk.y = pkrtz(r2, r3);
                pk.z = pkrtz(r4, r5);
                pk.w = pkrtz(r6, r7);
                *(float4*)&act_sh[my_oct * 128 + ((b ^ my_oct) & 15) * 8] = pk;
            }
        }
    };

    // one deriv task (o = d_o, given b), dec in regs
    auto derivB = [&](int b) {
        float p0 = 0.f, p1 = 0.f, q0 = 0.f, q1 = 0.f;
        #pragma unroll
        for (int c = 0; c < 5; ++c) {
            int oct = d_o * 5 + c;
            float4 af = *(const float4*)&act_sh[oct * 128 + ((b ^ oct) & 15) * 8];
            p0 = fdot2f(af.x, dd0[c].x, p0); p1 = fdot2f(af.y, dd0[c].y, p1);
            p0 = fdot2f(af.z, dd0[c].z, p0); p1 = fdot2f(af.w, dd0[c].w, p1);
            q0 = fdot2f(af.x, dd1[c].x, q0); q1 = fdot2f(af.y, dd1[c].y, q1);
            q0 = fdot2f(af.z, dd1[c].z, q0); q1 = fdot2f(af.w, dd1[c].w, q1);
        }
        float2 osv = *(const float2*)&os_sh[d_o * OS_STR + b * 2];
        osv.x += 0.001f * (p0 + p1);
        osv.y += 0.001f * (q0 + q1);
        *(float2*)&os_sh[d_o * OS_STR + b * 2] = osv;
    };

    phaseA();                   // act(0)
    __syncthreads();

    for (int s = 0; s < NSTEP; ++s) {
        // ---- P1: MFMA(t<256) | deriv | fc5/limb/store(s-1) on t>=1008 ----
        if (t < 256) {
            v4f c0 = {0.f, 0.f, 0.f, 0.f}, c1 = {0.f, 0.f, 0.f, 0.f};
            #pragma unroll
            for (int ks = 0; ks < 16; ++ks) {
                v8h a = *(const v8h*)&act_sh[a_base + ks * 512 + ax[ks & 3]];
                c0 = __builtin_amdgcn_mfma_f32_16x16x32_f16(a, wr[ks],      c0, 0, 0, 0);
                c1 = __builtin_amdgcn_mfma_f32_16x16x32_f16(a, wr[16 + ks], c1, 0, 0, 0);
            }
            *(v4f*)&part[(wv * 2 + 0) * 256 + lidx * 4] = c0;
            *(v4f*)&part[(wv * 2 + 1) * 256 + lidx * 4] = c1;
        } else if (di < 750) {
            derivB(d_r);
            if (d_r == 14) derivB(15);
        } else if (cb >= 0 && cb < NB && s > 0) {
            // fc5 + limb ODE + stores for step s-1 (b1s from P2 of s-1)
            float a0 = bs0, a1 = bs1;
            #pragma unroll
            for (int i = 0; i < 32; i += 4) {
                float4 bv = *(const float4*)&b1s[cb * B1STR + i];
                a0 = dot4(bv, *(const float4*)&fc5_w[i],      a0);
                a1 = dot4(bv, *(const float4*)&fc5_w[32 + i], a1);
            }
            float f1v = fmaxf(a0, 0.f) * 50.f * fmaxf(l1 - 0.05f, 0.f);
            float f2v = fmaxf(a1, 0.f) * 50.f * fmaxf(l2 - 0.05f, 0.f);
            float domega = (0.02f * (f2v - f1v) - 0.01f * omega) / 0.001f;
            float dl1 = ((0.1f - 0.02f * theta) - l1) / 0.05f;
            float dl2 = ((0.1f + 0.02f * theta) - l2) / 0.05f;
            float pos = fmaf(0.001f, omega,  theta);
            float vel = fmaf(0.001f, domega, omega);
            l1 = fmaf(0.001f, dl1, l1);
            l2 = fmaf(0.001f, dl2, l2);
            bool inb = (pos > -HALF_PI) && (pos < HALF_PI);
            float posc = fminf(fmaxf(pos, -HALF_PI), HALF_PI);
            vel = inb ? vel : 0.f;
            theta = posc;
            omega = vel;
            float4 lo; lo.x = posc; lo.y = vel; lo.z = l1; lo.w = l2;
            *(float4*)&out[((size_t)(s - 1) * BATCH + (b0 + cb)) * 4] = lo;
            float2 ao; ao.x = a0; ao.y = a1;
            *(float2*)&out[ACT_OFF + ((size_t)(s - 1) * BATCH + (b0 + cb)) * 2] = ao;
        }
        __syncthreads();

        // ---- P2: t<512: R (4 partials) -> b1s; all: phaseA(s+1) ----
        if (t < 512) {
            int b = t & 15, j = t >> 4;         // b 0..15, j 0..31
            int g = j >> 4, n = j & 15;
            int Lp = (b >> 2) * 16 + (n ^ ((b >> 2) << 2));   // un-swizzle
            int base = g * 256 + Lp * 4 + (b & 3);
            float sum = ((part[base] + part[512 + base])
                       + part[1024 + base]) + part[1536 + base];
            b1s[b * B1STR + j] = fmaxf(sum + fc4_b[j], 0.f);
        }
        phaseA();
        __syncthreads();
    }

    // ---- tail: fc5 + limb + store for the final step ----
    if (cb >= 0 && cb < NB) {
        const int s = NSTEP - 1;
        float a0 = bs0, a1 = bs1;
        #pragma unroll
        for (int i = 0; i < 32; i += 4) {
            float4 bv = *(const float4*)&b1s[cb * B1STR + i];
            a0 = dot4(bv, *(const float4*)&fc5_w[i],      a0);
            a1 = dot4(bv, *(const float4*)&fc5_w[32 + i], a1);
        }
        float f1v = fmaxf(a0, 0.f) * 50.f * fmaxf(l1 - 0.05f, 0.f);
        float f2v = fmaxf(a1, 0.f) * 50.f * fmaxf(l2 - 0.05f, 0.f);
        float domega = (0.02f * (f2v - f1v) - 0.01f * omega) / 0.001f;
        float dl1 = ((0.1f - 0.02f * theta) - l1) / 0.05f;
        float dl2 = ((0.1f + 0.02f * theta) - l2) / 0.05f;
        float pos = fmaf(0.001f, omega,  theta);
        float vel = fmaf(0.001f, domega, omega);
        l1 = fmaf(0.001f, dl1, l1);
        l2 = fmaf(0.001f, dl2, l2);
        bool inb = (pos > -HALF_PI) && (pos < HALF_PI);
        float posc = fminf(fmaxf(pos, -HALF_PI), HALF_PI);
        vel = inb ? vel : 0.f;
        float4 lo; lo.x = posc; lo.y = vel; lo.z = l1; lo.w = l2;
        *(float4*)&out[((size_t)s * BATCH + (b0 + cb)) * 4] = lo;
        float2 ao; ao.x = a0; ao.y = a1;
        *(float2*)&out[ACT_OFF + ((size_t)s * BATCH + (b0 + cb)) * 2] = ao;
    }
}

extern "C" void kernel_launch(void* const* d_in, const int* in_sizes, int n_in,
                              void* d_out, int out_size, void* d_ws, size_t ws_size,
                              hipStream_t stream) {
    (void)in_sizes; (void)n_in; (void)d_ws; (void)ws_size; (void)out_size;
    const float* x_     = (const float*)d_in[0];
    const float* fc1_w  = (const float*)d_in[1];
    const float* fc1_b  = (const float*)d_in[2];
    const float* fc2_w  = (const float*)d_in[3];
    const float* fc2_b  = (const float*)d_in[4];
    const float* fc3_w  = (const float*)d_in[5];
    const float* fc3_b  = (const float*)d_in[6];
    const float* fcd_w  = (const float*)d_in[7];
    const float* fcd_b  = (const float*)d_in[8];
    const float* enc    = (const float*)d_in[9];
    const float* oscb   = (const float*)d_in[10];
    const float* dec    = (const float*)d_in[11];
    const float* fc4_w  = (const float*)d_in[12];
    const float* fc4_b  = (const float*)d_in[13];
    const float* fc5_w  = (const float*)d_in[14];
    const float* fc5_b  = (const float*)d_in[15];
    float* out = (float*)d_out;

    hipLaunchKernelGGL(prep_f16, dim3(256), dim3(256), 0, stream, fc4_w);
    hipLaunchKernelGGL(net_main, dim3(BATCH / NB), dim3(NTHR), 0, stream,
                       x_, fc1_w, fc1_b, fc2_w, fc2_b, fc3_w, fc3_b,
                       fcd_w, fcd_b, enc, oscb, dec, fc4_b,
                       fc5_w, fc5_b, out);
}

// Round 13
// 4059.731 us; speedup vs baseline: 3.4633x; 3.4633x over previous
//
#include <hip/hip_runtime.h>

#define NTHR 1024
#define NB   16
#define NOSC 50
#define NPER 40
#define KTOT 2000
#define KPAD 2048
#define NSTEP 700
#define BATCH 4096
#define B1STR 36
#define OS_STR 36
#define HALF_PI 1.57079632679489662f
#define ACT_OFF ((size_t)NSTEP * BATCH * 4)

typedef _Float16 v8h __attribute__((ext_vector_type(8)));
typedef _Float16 h2_t __attribute__((ext_vector_type(2)));
typedef float v4f __attribute__((ext_vector_type(4)));

__device__ _Float16 g_w4[32 * KPAD];    // fc4_w in f16, zero-padded K 2000->2048

__device__ __forceinline__ float fdot2f(float a_bits, float b_bits, float acc) {
    h2_t a = __builtin_bit_cast(h2_t, a_bits);
    h2_t b = __builtin_bit_cast(h2_t, b_bits);
#if __has_builtin(__builtin_amdgcn_fdot2)
    return __builtin_amdgcn_fdot2(a, b, acc, false);
#else
    return fmaf((float)a[0], (float)b[0], fmaf((float)a[1], (float)b[1], acc));
#endif
}

__device__ __forceinline__ float dot4(float4 a, float4 b, float acc) {
    acc = fmaf(a.x, b.x, acc);
    acc = fmaf(a.y, b.y, acc);
    acc = fmaf(a.z, b.z, acc);
    acc = fmaf(a.w, b.w, acc);
    return acc;
}

__device__ __forceinline__ float pkrtz(float a, float b) {
    auto q = __builtin_amdgcn_cvt_pkrtz(a, b);
    return __builtin_bit_cast(float, q);
}

// pack 2 f32 -> 2 f16 with round-to-nearest (matches old (_Float16) LDS staging)
__device__ __forceinline__ float cvt2rtn(float a, float b) {
    h2_t u; u[0] = (_Float16)a; u[1] = (_Float16)b;
    return __builtin_bit_cast(float, u);
}

__global__ void prep_f16(const float* __restrict__ fc4_w) {
    int tid = blockIdx.x * blockDim.x + threadIdx.x;   // 65536 total
    int j = tid >> 11, k = tid & 2047;
    g_w4[j * KPAD + k] = (k < KTOT) ? (_Float16)fc4_w[j * KTOT + k] : (_Float16)0.f;
}

// act layout: element (b, k): oct = k>>3, j = k&7, slot = (b ^ oct) & 15
//   f16 idx = oct*128 + slot*8 + j
// r12 post-mortem: wr[32] (128 VGPR) spilled -> FETCH 20.8 GB, 7x slower.
// Known-safe sizes: wr[8] (r10, clean), wr[16] (r9, parks in AGPRs).
// This round = r12's wave-op reduction at wr[16]:
//  - MFMA on t<512: 8 waves x K=256 (16 MFMAs, wr[16]); part 16->8 partials
//    => part-writes 32->16 wave-ops, R reads 16->8/thread.
//  - deriv on t>=512: i<288 -> TWO tasks of same o (b=2(i&7), +1; one dd set,
//    os update fused to one float4 RMW); i>=288 -> one task o=(i+288)>>4.
//  - fc5/limb on t in [1008,1024) after their deriv task (oct>=252: no phaseA).
// 2 barriers/step:
//   P1: MFMA(t<512) | deriv(t>=512) (+ fc5/limb/store(s-1) tail)
//   P2: R8(t<512); phaseA(s+1) on all
__global__ __launch_bounds__(NTHR)
void net_main(const float* __restrict__ x,
              const float* __restrict__ fc1_w, const float* __restrict__ fc1_b,
              const float* __restrict__ fc2_w, const float* __restrict__ fc2_b,
              const float* __restrict__ fc3_w, const float* __restrict__ fc3_b,
              const float* __restrict__ fcd_w, const float* __restrict__ fcd_b,
              const float* __restrict__ enc,   const float* __restrict__ osc_bias,
              const float* __restrict__ dec,
              const float* __restrict__ fc4_b,
              const float* __restrict__ fc5_w, const float* __restrict__ fc5_b,
              float* __restrict__ out)
{
    __shared__ __align__(16) _Float16 act_sh[256 * 128];  // 64 KB, frag-major
    __shared__ __align__(16) float part[8 * 2 * 256];     // 16 KB, MFMA partials (swizzled)
    __shared__ __align__(16) float os_sh[NOSC * OS_STR];  // 7.2 KB [o][b*2+d], padded stride
    __shared__ __align__(16) float b1s[NB * B1STR];
    __shared__ __align__(16) float dir[NB * 2];

    const int t    = threadIdx.x;
    const int lane = t & 63;
    const int wv   = t >> 6;            // 0..15
    const int b0   = blockIdx.x * NB;

    float* h  = (float*)act_sh;         // [NB][128] f32 temp (pre-loop only)
    float* h2 = (float*)act_sh + NB * 128;

    // ---------- precompute: fc1 ----------
    #pragma unroll
    for (int ii = 0; ii < 2; ++ii) {
        int task = t + ii * NTHR;       // 2048 tasks
        int b = task >> 7, i = task & 127;
        float x0 = x[(b0 + b) * 2 + 0];
        float x1 = x[(b0 + b) * 2 + 1];
        float v = fmaf(x0, fc1_w[2 * i], fmaf(x1, fc1_w[2 * i + 1], fc1_b[i]));
        h[b * 128 + i] = fmaxf(v, 0.f);
    }
    __syncthreads();
    // ---------- precompute: fc2 -> h2, fcd -> dir ----------
    #pragma unroll
    for (int ii = 0; ii < 2; ++ii) {
        int task = t + ii * NTHR;
        int b = task >> 7, i = task & 127;
        float acc = fc2_b[i];
        #pragma unroll 4
        for (int k = 0; k < 128; k += 4)
            acc = dot4(*(const float4*)&fc2_w[i * 128 + k],
                       *(const float4*)&h[b * 128 + k], acc);
        h2[b * 128 + i] = fmaxf(acc, 0.f);
    }
    if (t < NB * 2) {
        int b = t >> 1, j = t & 1;
        float acc = fcd_b[j];
        #pragma unroll 4
        for (int k = 0; k < 128; k += 4)
            acc = dot4(*(const float4*)&fcd_w[j * 128 + k],
                       *(const float4*)&h[b * 128 + k], acc);
        dir[b * 2 + j] = acc;
    }
    __syncthreads();
    // ---------- precompute: fc3 -> os_sh ----------
    #pragma unroll
    for (int ii = 0; ii < 2; ++ii) {
        int task = t + ii * NTHR;
        if (task < NOSC * NB * 2) {     // 1600 tasks
            int o = task >> 5, r = task & 31, b = r >> 1;
            int row = o * 2 + (r & 1);
            float acc = fc3_b[row];
            #pragma unroll 4
            for (int k = 0; k < 128; k += 4)
                acc = dot4(*(const float4*)&fc3_w[row * 128 + k],
                           *(const float4*)&h2[b * 128 + k], acc);
            os_sh[o * OS_STR + r] = acc;
        }
    }
    // ---------- enc/bias -> per-thread registers (oct fixed per thread) ----------
    const int my_oct = t >> 2;          // 0..255; threads with oct>=250 idle in phaseA
    float4 e0 = {0,0,0,0}, e1 = {0,0,0,0}, e2 = {0,0,0,0}, e3 = {0,0,0,0};
    float4 bi0 = {0,0,0,0}, bi1 = {0,0,0,0};
    int my_o = 0;
    if (my_oct < 250) {
        const float4* ep = (const float4*)&enc[my_oct * 16];
        e0 = ep[0]; e1 = ep[1]; e2 = ep[2]; e3 = ep[3];
        const float4* bp = (const float4*)&osc_bias[my_oct * 8];
        bi0 = bp[0]; bi1 = bp[1];
        my_o = my_oct / 5;
    }
    // ---------- dec -> per-thread registers (deriv threads t >= 512) ----------
    const int di = t - 512;
    int d_o = 0, d_b = 0;
    bool dual = false;
    float4 dd0[5], dd1[5];
    if (di >= 0) {
        if (di < 288) { dual = true; d_o = di >> 3; d_b = (di & 7) * 2; }
        else          { int task = di + 288; d_o = task >> 4; d_b = task & 15; }
        const float* d0p = &dec[(d_o * 2 + 0) * 40];
        const float* d1p = &dec[(d_o * 2 + 1) * 40];
        #pragma unroll
        for (int c = 0; c < 5; ++c) {
            dd0[c].x = cvt2rtn(d0p[c*8+0], d0p[c*8+1]);
            dd0[c].y = cvt2rtn(d0p[c*8+2], d0p[c*8+3]);
            dd0[c].z = cvt2rtn(d0p[c*8+4], d0p[c*8+5]);
            dd0[c].w = cvt2rtn(d0p[c*8+6], d0p[c*8+7]);
            dd1[c].x = cvt2rtn(d1p[c*8+0], d1p[c*8+1]);
            dd1[c].y = cvt2rtn(d1p[c*8+2], d1p[c*8+3]);
            dd1[c].z = cvt2rtn(d1p[c*8+4], d1p[c*8+5]);
            dd1[c].w = cvt2rtn(d1p[c*8+6], d1p[c*8+7]);
        }
    }
    // ---------- limb init (threads 1008..1023 own the ODE + stores) ----------
    float theta = 0.f, omega = 0.f, l1 = 0.f, l2 = 0.f, bs0 = 0.f, bs1 = 0.f;
    const int cb = t - 1008;            // 0..15 on tail of wave 15
    if (cb >= 0 && cb < NB) {
        theta = x[(b0 + cb) * 2 + 0];
        l1 = fmaf(-0.02f, theta, 0.1f);
        l2 = fmaf( 0.02f, theta, 0.1f);
    }
    __syncthreads();
    if (cb >= 0 && cb < NB) {
        bs0 = dir[cb * 2 + 0] + fc5_b[0];
        bs1 = dir[cb * 2 + 1] + fc5_b[1];
    }
    // zero act padding (octets 250..255 -> f16 idx [32000, 32768))
    if (t < 768) act_sh[32000 + t] = (_Float16)0.f;

    // ---------- MFMA setup: 8 waves x K=256, weights in regs/AGPRs ----------
    const int n_col = lane & 15, quad = lane >> 4;
    const int lidx  = lane ^ (quad << 2);           // part write swizzle
    int a_off[8];
    #pragma unroll
    for (int ks = 0; ks < 8; ++ks) {
        int oct = wv * 32 + ks * 4 + quad;          // valid for wv<8
        a_off[ks] = (oct & 255) * 128 + ((n_col ^ (oct & 15)) * 8);
    }
    v8h wr[16];                         // B-fragments for 16 MFMAs (AGPR-parked)
    if (t < 512) {
        const _Float16* wp = &g_w4[n_col * KPAD + wv * 256 + quad * 8];
        #pragma unroll
        for (int ks = 0; ks < 8; ++ks) {
            wr[ks]     = *(const v8h*)&wp[ks * 32];
            wr[8 + ks] = *(const v8h*)&wp[16 * KPAD + ks * 32];
        }
    }

    // ---------- phase A: act = relu(enc . os + bias), enc/bias in REGISTERS ----------
    // thread covers b = (t&3)*4 + ii, ii=0..3 -> slot bijective per 16-lane group
    auto phaseA = [&]() {
        if (my_oct < 250) {
            const int i4 = (t & 3) << 2;
            float4 osA = *(const float4*)&os_sh[my_o * OS_STR + i4 * 2];      // b=i4+0,1
            float4 osB = *(const float4*)&os_sh[my_o * OS_STR + i4 * 2 + 4];  // b=i4+2,3
            #pragma unroll
            for (int ii = 0; ii < 4; ++ii) {
                int b = i4 + ii;
                float osx = (ii == 0) ? osA.x : (ii == 1) ? osA.z : (ii == 2) ? osB.x : osB.z;
                float osy = (ii == 0) ? osA.y : (ii == 1) ? osA.w : (ii == 2) ? osB.y : osB.w;
                float r0 = fmaxf(fmaf(e0.x, osx, fmaf(e0.y, osy, bi0.x)), 0.f);
                float r1 = fmaxf(fmaf(e0.z, osx, fmaf(e0.w, osy, bi0.y)), 0.f);
                float r2 = fmaxf(fmaf(e1.x, osx, fmaf(e1.y, osy, bi0.z)), 0.f);
                float r3 = fmaxf(fmaf(e1.z, osx, fmaf(e1.w, osy, bi0.w)), 0.f);
                float r4 = fmaxf(fmaf(e2.x, osx, fmaf(e2.y, osy, bi1.x)), 0.f);
                float r5 = fmaxf(fmaf(e2.z, osx, fmaf(e2.w, osy, bi1.y)), 0.f);
                float r6 = fmaxf(fmaf(e3.x, osx, fmaf(e3.y, osy, bi1.z)), 0.f);
                float r7 = fmaxf(fmaf(e3.z, osx, fmaf(e3.w, osy, bi1.w)), 0.f);
                float4 pk;
                pk.x = pkrtz(r0, r1);
                pk.y = pkrtz(r2, r3);
                pk.z = pkrtz(r4, r5);
                pk.w = pkrtz(r6, r7);
                *(float4*)&act_sh[my_oct * 128 + ((b ^ my_oct) & 15) * 8] = pk;
            }
        }
    };

    // deriv dot for one b: returns (p, q) = (d0 . act_b, d1 . act_b)
    auto derivDot = [&](int b, float& pOut, float& qOut) {
        float p0 = 0.f, p1 = 0.f, q0 = 0.f, q1 = 0.f;
        #pragma unroll
        for (int c = 0; c < 5; ++c) {
            int oct = d_o * 5 + c;
            float4 af = *(const float4*)&act_sh[oct * 128 + ((b ^ oct) & 15) * 8];
            p0 = fdot2f(af.x, dd0[c].x, p0); p1 = fdot2f(af.y, dd0[c].y, p1);
            p0 = fdot2f(af.z, dd0[c].z, p0); p1 = fdot2f(af.w, dd0[c].w, p1);
            q0 = fdot2f(af.x, dd1[c].x, q0); q1 = fdot2f(af.y, dd1[c].y, q1);
            q0 = fdot2f(af.z, dd1[c].z, q0); q1 = fdot2f(af.w, dd1[c].w, q1);
        }
        pOut = p0 + p1;
        qOut = q0 + q1;
    };

    phaseA();                   // act(0)
    __syncthreads();

    for (int s = 0; s < NSTEP; ++s) {
        // ---- P1: MFMA(t<512) | deriv(t>=512) + fc5/limb/store(s-1) tail ----
        if (t < 512) {
            v4f c0 = {0.f, 0.f, 0.f, 0.f}, c1 = {0.f, 0.f, 0.f, 0.f};
            #pragma unroll
            for (int ks = 0; ks < 8; ++ks) {
                v8h a = *(const v8h*)&act_sh[a_off[ks]];
                c0 = __builtin_amdgcn_mfma_f32_16x16x32_f16(a, wr[ks],     c0, 0, 0, 0);
                c1 = __builtin_amdgcn_mfma_f32_16x16x32_f16(a, wr[8 + ks], c1, 0, 0, 0);
            }
            *(v4f*)&part[(wv * 2 + 0) * 256 + lidx * 4] = c0;
            *(v4f*)&part[(wv * 2 + 1) * 256 + lidx * 4] = c1;
        } else {
            if (dual) {
                float pA, qA, pB, qB;
                derivDot(d_b,     pA, qA);
                derivDot(d_b + 1, pB, qB);
                float4 osv = *(const float4*)&os_sh[d_o * OS_STR + d_b * 2];
                osv.x += 0.001f * pA;
                osv.y += 0.001f * qA;
                osv.z += 0.001f * pB;
                osv.w += 0.001f * qB;
                *(float4*)&os_sh[d_o * OS_STR + d_b * 2] = osv;
            } else {
                float p, q;
                derivDot(d_b, p, q);
                float2 osv = *(const float2*)&os_sh[d_o * OS_STR + d_b * 2];
                osv.x += 0.001f * p;
                osv.y += 0.001f * q;
                *(float2*)&os_sh[d_o * OS_STR + d_b * 2] = osv;
            }
            if (cb >= 0 && cb < NB && s > 0) {
                // fc5 + limb ODE + stores for step s-1 (b1s from P2 of s-1)
                float a0 = bs0, a1 = bs1;
                #pragma unroll
                for (int i = 0; i < 32; i += 4) {
                    float4 bv = *(const float4*)&b1s[cb * B1STR + i];
                    a0 = dot4(bv, *(const float4*)&fc5_w[i],      a0);
                    a1 = dot4(bv, *(const float4*)&fc5_w[32 + i], a1);
                }
                float f1v = fmaxf(a0, 0.f) * 50.f * fmaxf(l1 - 0.05f, 0.f);
                float f2v = fmaxf(a1, 0.f) * 50.f * fmaxf(l2 - 0.05f, 0.f);
                float domega = (0.02f * (f2v - f1v) - 0.01f * omega) / 0.001f;
                float dl1 = ((0.1f - 0.02f * theta) - l1) / 0.05f;
                float dl2 = ((0.1f + 0.02f * theta) - l2) / 0.05f;
                float pos = fmaf(0.001f, omega,  theta);
                float vel = fmaf(0.001f, domega, omega);
                l1 = fmaf(0.001f, dl1, l1);
                l2 = fmaf(0.001f, dl2, l2);
                bool inb = (pos > -HALF_PI) && (pos < HALF_PI);
                float posc = fminf(fmaxf(pos, -HALF_PI), HALF_PI);
                vel = inb ? vel : 0.f;
                theta = posc;
                omega = vel;
                float4 lo; lo.x = posc; lo.y = vel; lo.z = l1; lo.w = l2;
                *(float4*)&out[((size_t)(s - 1) * BATCH + (b0 + cb)) * 4] = lo;
                float2 ao; ao.x = a0; ao.y = a1;
                *(float2*)&out[ACT_OFF + ((size_t)(s - 1) * BATCH + (b0 + cb)) * 2] = ao;
            }
        }
        __syncthreads();

        // ---- P2: t<512: R (8 partials) -> b1s; all: phaseA(s+1) ----
        if (t < 512) {
            int b = t & 15, j = t >> 4;         // b 0..15, j 0..31
            int g = j >> 4, n = j & 15;
            int Lp = (b >> 2) * 16 + (n ^ ((b >> 2) << 2));   // un-swizzle
            int base = g * 256 + Lp * 4 + (b & 3);
            float sum = 0.f;
            #pragma unroll
            for (int w = 0; w < 8; ++w)
                sum += part[w * 512 + base];
            b1s[b * B1STR + j] = fmaxf(sum + fc4_b[j], 0.f);
        }
        phaseA();
        __syncthreads();
    }

    // ---- tail: fc5 + limb + store for the final step ----
    if (cb >= 0 && cb < NB) {
        const int s = NSTEP - 1;
        float a0 = bs0, a1 = bs1;
        #pragma unroll
        for (int i = 0; i < 32; i += 4) {
            float4 bv = *(const float4*)&b1s[cb * B1STR + i];
            a0 = dot4(bv, *(const float4*)&fc5_w[i],      a0);
            a1 = dot4(bv, *(const float4*)&fc5_w[32 + i], a1);
        }
        float f1v = fmaxf(a0, 0.f) * 50.f * fmaxf(l1 - 0.05f, 0.f);
        float f2v = fmaxf(a1, 0.f) * 50.f * fmaxf(l2 - 0.05f, 0.f);
        float domega = (0.02f * (f2v - f1v) - 0.01f * omega) / 0.001f;
        float dl1 = ((0.1f - 0.02f * theta) - l1) / 0.05f;
        float dl2 = ((0.1f + 0.02f * theta) - l2) / 0.05f;
        float pos = fmaf(0.001f, omega,  theta);
        float vel = fmaf(0.001f, domega, omega);
        l1 = fmaf(0.001f, dl1, l1);
        l2 = fmaf(0.001f, dl2, l2);
        bool inb = (pos > -HALF_PI) && (pos < HALF_PI);
        float posc = fminf(fmaxf(pos, -HALF_PI), HALF_PI);
        vel = inb ? vel : 0.f;
        float4 lo; lo.x = posc; lo.y = vel; lo.z = l1; lo.w = l2;
        *(float4*)&out[((size_t)s * BATCH + (b0 + cb)) * 4] = lo;
        float2 ao; ao.x = a0; ao.y = a1;
        *(float2*)&out[ACT_OFF + ((size_t)s * BATCH + (b0 + cb)) * 2] = ao;
    }
}

extern "C" void kernel_launch(void* const* d_in, const int* in_sizes, int n_in,
                              void* d_out, int out_size, void* d_ws, size_t ws_size,
                              hipStream_t stream) {
    (void)in_sizes; (void)n_in; (void)d_ws; (void)ws_size; (void)out_size;
    const float* x_     = (const float*)d_in[0];
    const float* fc1_w  = (const float*)d_in[1];
    const float* fc1_b  = (const float*)d_in[2];
    const float* fc2_w  = (const float*)d_in[3];
    const float* fc2_b  = (const float*)d_in[4];
    const float* fc3_w  = (const float*)d_in[5];
    const float* fc3_b  = (const float*)d_in[6];
    const float* fcd_w  = (const float*)d_in[7];
    const float* fcd_b  = (const float*)d_in[8];
    const float* enc    = (const float*)d_in[9];
    const float* oscb   = (const float*)d_in[10];
    const float* dec    = (const float*)d_in[11];
    const float* fc4_w  = (const float*)d_in[12];
    const float* fc4_b  = (const float*)d_in[13];
    const float* fc5_w  = (const float*)d_in[14];
    const float* fc5_b  = (const float*)d_in[15];
    float* out = (float*)d_out;

    hipLaunchKernelGGL(prep_f16, dim3(256), dim3(256), 0, stream, fc4_w);
    hipLaunchKernelGGL(net_main, dim3(BATCH / NB), dim3(NTHR), 0, stream,
                       x_, fc1_w, fc1_b, fc2_w, fc2_b, fc3_w, fc3_b,
                       fcd_w, fcd_b, enc, oscb, dec, fc4_b,
                       fc5_w, fc5_b, out);
}

// Round 14
// 1995.301 us; speedup vs baseline: 7.0467x; 2.0346x over previous
//
#include <hip/hip_runtime.h>

#define NTHR 1024
#define NB   16
#define NOSC 50
#define NPER 40
#define KTOT 2000
#define KPAD 2048
#define NSTEP 700
#define BATCH 4096
#define B1STR 36
#define OS_STR 36
#define HALF_PI 1.57079632679489662f
#define ACT_OFF ((size_t)NSTEP * BATCH * 4)

typedef _Float16 v8h __attribute__((ext_vector_type(8)));
typedef _Float16 h2_t __attribute__((ext_vector_type(2)));
typedef float v4f __attribute__((ext_vector_type(4)));

__device__ _Float16 g_w4[32 * KPAD];    // fc4_w in f16, zero-padded K 2000->2048

__device__ __forceinline__ float fdot2f(float a_bits, float b_bits, float acc) {
    h2_t a = __builtin_bit_cast(h2_t, a_bits);
    h2_t b = __builtin_bit_cast(h2_t, b_bits);
#if __has_builtin(__builtin_amdgcn_fdot2)
    return __builtin_amdgcn_fdot2(a, b, acc, false);
#else
    return fmaf((float)a[0], (float)b[0], fmaf((float)a[1], (float)b[1], acc));
#endif
}

__device__ __forceinline__ float dot4(float4 a, float4 b, float acc) {
    acc = fmaf(a.x, b.x, acc);
    acc = fmaf(a.y, b.y, acc);
    acc = fmaf(a.z, b.z, acc);
    acc = fmaf(a.w, b.w, acc);
    return acc;
}

__device__ __forceinline__ float pkrtz(float a, float b) {
    auto q = __builtin_amdgcn_cvt_pkrtz(a, b);
    return __builtin_bit_cast(float, q);
}

// pack 2 f32 -> 2 f16 with round-to-nearest (matches old (_Float16) LDS staging)
__device__ __forceinline__ float cvt2rtn(float a, float b) {
    h2_t u; u[0] = (_Float16)a; u[1] = (_Float16)b;
    return __builtin_bit_cast(float, u);
}

__global__ void prep_f16(const float* __restrict__ fc4_w) {
    int tid = blockIdx.x * blockDim.x + threadIdx.x;   // 65536 total
    int j = tid >> 11, k = tid & 2047;
    g_w4[j * KPAD + k] = (k < KTOT) ? (_Float16)fc4_w[j * KTOT + k] : (_Float16)0.f;
}

// act layout: element (b, k): oct = k>>3, j = k&7, slot = (b ^ oct) & 15
//   f16 idx = oct*128 + slot*8 + j
// r13 post-mortem: reg budget = 128/wave (VGPR+AGPR unified, 16 waves/CU).
// wr[16] (64) + dd (40) as SEPARATE variables are both live across the loop
// -> union 160+ regs -> spill (FETCH 4.8 GB). Fix: ONE v4f st[16] written in
// mutually-exclusive branches (phi-merge -> 64 regs total):
//   t<512 : st = 16 B-fragments (MFMA weights)
//   t>=512: st[0..4]=dd0, st[5..9]=dd1 (deriv dec rows)
// Schedule (r13): P1: MFMA(t<512, 8 waves x K=256) | deriv(t>=512)
//                     (+ fc5/limb/store(s-1) on t in [1008,1024))
//                 P2: R8(t<512); phaseA(s+1) on all
__global__ __launch_bounds__(NTHR)
void net_main(const float* __restrict__ x,
              const float* __restrict__ fc1_w, const float* __restrict__ fc1_b,
              const float* __restrict__ fc2_w, const float* __restrict__ fc2_b,
              const float* __restrict__ fc3_w, const float* __restrict__ fc3_b,
              const float* __restrict__ fcd_w, const float* __restrict__ fcd_b,
              const float* __restrict__ enc,   const float* __restrict__ osc_bias,
              const float* __restrict__ dec,
              const float* __restrict__ fc4_b,
              const float* __restrict__ fc5_w, const float* __restrict__ fc5_b,
              float* __restrict__ out)
{
    __shared__ __align__(16) _Float16 act_sh[256 * 128];  // 64 KB, frag-major
    __shared__ __align__(16) float part[8 * 2 * 256];     // 16 KB, MFMA partials (swizzled)
    __shared__ __align__(16) float os_sh[NOSC * OS_STR];  // 7.2 KB [o][b*2+d], padded stride
    __shared__ __align__(16) float b1s[NB * B1STR];
    __shared__ __align__(16) float dir[NB * 2];

    const int t    = threadIdx.x;
    const int lane = t & 63;
    const int wv   = t >> 6;            // 0..15
    const int b0   = blockIdx.x * NB;

    float* h  = (float*)act_sh;         // [NB][128] f32 temp (pre-loop only)
    float* h2 = (float*)act_sh + NB * 128;

    // ---------- precompute: fc1 ----------
    #pragma unroll
    for (int ii = 0; ii < 2; ++ii) {
        int task = t + ii * NTHR;       // 2048 tasks
        int b = task >> 7, i = task & 127;
        float x0 = x[(b0 + b) * 2 + 0];
        float x1 = x[(b0 + b) * 2 + 1];
        float v = fmaf(x0, fc1_w[2 * i], fmaf(x1, fc1_w[2 * i + 1], fc1_b[i]));
        h[b * 128 + i] = fmaxf(v, 0.f);
    }
    __syncthreads();
    // ---------- precompute: fc2 -> h2, fcd -> dir ----------
    #pragma unroll
    for (int ii = 0; ii < 2; ++ii) {
        int task = t + ii * NTHR;
        int b = task >> 7, i = task & 127;
        float acc = fc2_b[i];
        #pragma unroll 4
        for (int k = 0; k < 128; k += 4)
            acc = dot4(*(const float4*)&fc2_w[i * 128 + k],
                       *(const float4*)&h[b * 128 + k], acc);
        h2[b * 128 + i] = fmaxf(acc, 0.f);
    }
    if (t < NB * 2) {
        int b = t >> 1, j = t & 1;
        float acc = fcd_b[j];
        #pragma unroll 4
        for (int k = 0; k < 128; k += 4)
            acc = dot4(*(const float4*)&fcd_w[j * 128 + k],
                       *(const float4*)&h[b * 128 + k], acc);
        dir[b * 2 + j] = acc;
    }
    __syncthreads();
    // ---------- precompute: fc3 -> os_sh ----------
    #pragma unroll
    for (int ii = 0; ii < 2; ++ii) {
        int task = t + ii * NTHR;
        if (task < NOSC * NB * 2) {     // 1600 tasks
            int o = task >> 5, r = task & 31, b = r >> 1;
            int row = o * 2 + (r & 1);
            float acc = fc3_b[row];
            #pragma unroll 4
            for (int k = 0; k < 128; k += 4)
                acc = dot4(*(const float4*)&fc3_w[row * 128 + k],
                           *(const float4*)&h2[b * 128 + k], acc);
            os_sh[o * OS_STR + r] = acc;
        }
    }
    // ---------- enc/bias -> per-thread registers (oct fixed per thread) ----------
    const int my_oct = t >> 2;          // 0..255; threads with oct>=250 idle in phaseA
    float4 e0 = {0,0,0,0}, e1 = {0,0,0,0}, e2 = {0,0,0,0}, e3 = {0,0,0,0};
    float4 bi0 = {0,0,0,0}, bi1 = {0,0,0,0};
    int my_o = 0;
    if (my_oct < 250) {
        const float4* ep = (const float4*)&enc[my_oct * 16];
        e0 = ep[0]; e1 = ep[1]; e2 = ep[2]; e3 = ep[3];
        const float4* bp = (const float4*)&osc_bias[my_oct * 8];
        bi0 = bp[0]; bi1 = bp[1];
        my_o = my_oct / 5;
    }
    // ---------- deriv task mapping (threads t >= 512) ----------
    const int di = t - 512;
    int d_o = 0, d_b = 0;
    bool dual = false;
    if (di >= 0) {
        if (di < 288) { dual = true; d_o = di >> 3; d_b = (di & 7) * 2; }
        else          { int task = di + 288; d_o = task >> 4; d_b = task & 15; }
    }
    // ---------- limb init (threads 1008..1023 own the ODE + stores) ----------
    float theta = 0.f, omega = 0.f, l1 = 0.f, l2 = 0.f, bs0 = 0.f, bs1 = 0.f;
    const int cb = t - 1008;            // 0..15 on tail of wave 15
    if (cb >= 0 && cb < NB) {
        theta = x[(b0 + cb) * 2 + 0];
        l1 = fmaf(-0.02f, theta, 0.1f);
        l2 = fmaf( 0.02f, theta, 0.1f);
    }
    __syncthreads();
    if (cb >= 0 && cb < NB) {
        bs0 = dir[cb * 2 + 0] + fc5_b[0];
        bs1 = dir[cb * 2 + 1] + fc5_b[1];
    }
    // zero act padding (octets 250..255 -> f16 idx [32000, 32768))
    if (t < 768) act_sh[32000 + t] = (_Float16)0.f;

    // ---------- MFMA indices (8 GEMM waves x K=256) ----------
    const int n_col = lane & 15, quad = lane >> 4;
    const int lidx  = lane ^ (quad << 2);           // part write swizzle
    int a_off[8];
    #pragma unroll
    for (int ks = 0; ks < 8; ++ks) {
        int oct = wv * 32 + ks * 4 + quad;          // valid for wv<8
        a_off[ks] = (oct & 255) * 128 + ((n_col ^ (oct & 15)) * 8);
    }

    // ---------- OVERLAID state: st[16] = weights (t<512) OR dec rows (t>=512) ----------
    v4f st[16];
    if (t < 512) {
        const _Float16* wp = &g_w4[n_col * KPAD + wv * 256 + quad * 8];
        #pragma unroll
        for (int ks = 0; ks < 8; ++ks) {
            st[ks]     = __builtin_bit_cast(v4f, *(const v8h*)&wp[ks * 32]);
            st[8 + ks] = __builtin_bit_cast(v4f, *(const v8h*)&wp[16 * KPAD + ks * 32]);
        }
    } else {
        const float* d0p = &dec[(d_o * 2 + 0) * 40];
        const float* d1p = &dec[(d_o * 2 + 1) * 40];
        #pragma unroll
        for (int c = 0; c < 5; ++c) {
            v4f v0, v1;
            v0.x = cvt2rtn(d0p[c*8+0], d0p[c*8+1]);
            v0.y = cvt2rtn(d0p[c*8+2], d0p[c*8+3]);
            v0.z = cvt2rtn(d0p[c*8+4], d0p[c*8+5]);
            v0.w = cvt2rtn(d0p[c*8+6], d0p[c*8+7]);
            v1.x = cvt2rtn(d1p[c*8+0], d1p[c*8+1]);
            v1.y = cvt2rtn(d1p[c*8+2], d1p[c*8+3]);
            v1.z = cvt2rtn(d1p[c*8+4], d1p[c*8+5]);
            v1.w = cvt2rtn(d1p[c*8+6], d1p[c*8+7]);
            st[c]     = v0;
            st[5 + c] = v1;
        }
        #pragma unroll
        for (int i = 10; i < 16; ++i) st[i] = (v4f){0.f, 0.f, 0.f, 0.f};
    }

    // ---------- phase A: act = relu(enc . os + bias), enc/bias in REGISTERS ----------
    // thread covers b = (t&3)*4 + ii, ii=0..3 -> slot bijective per 16-lane group
    auto phaseA = [&]() {
        if (my_oct < 250) {
            const int i4 = (t & 3) << 2;
            float4 osA = *(const float4*)&os_sh[my_o * OS_STR + i4 * 2];      // b=i4+0,1
            float4 osB = *(const float4*)&os_sh[my_o * OS_STR + i4 * 2 + 4];  // b=i4+2,3
            #pragma unroll
            for (int ii = 0; ii < 4; ++ii) {
                int b = i4 + ii;
                float osx = (ii == 0) ? osA.x : (ii == 1) ? osA.z : (ii == 2) ? osB.x : osB.z;
                float osy = (ii == 0) ? osA.y : (ii == 1) ? osA.w : (ii == 2) ? osB.y : osB.w;
                float r0 = fmaxf(fmaf(e0.x, osx, fmaf(e0.y, osy, bi0.x)), 0.f);
                float r1 = fmaxf(fmaf(e0.z, osx, fmaf(e0.w, osy, bi0.y)), 0.f);
                float r2 = fmaxf(fmaf(e1.x, osx, fmaf(e1.y, osy, bi0.z)), 0.f);
                float r3 = fmaxf(fmaf(e1.z, osx, fmaf(e1.w, osy, bi0.w)), 0.f);
                float r4 = fmaxf(fmaf(e2.x, osx, fmaf(e2.y, osy, bi1.x)), 0.f);
                float r5 = fmaxf(fmaf(e2.z, osx, fmaf(e2.w, osy, bi1.y)), 0.f);
                float r6 = fmaxf(fmaf(e3.x, osx, fmaf(e3.y, osy, bi1.z)), 0.f);
                float r7 = fmaxf(fmaf(e3.z, osx, fmaf(e3.w, osy, bi1.w)), 0.f);
                float4 pk;
                pk.x = pkrtz(r0, r1);
                pk.y = pkrtz(r2, r3);
                pk.z = pkrtz(r4, r5);
                pk.w = pkrtz(r6, r7);
                *(float4*)&act_sh[my_oct * 128 + ((b ^ my_oct) & 15) * 8] = pk;
            }
        }
    };

    // deriv dot for one b using st[0..9] as dec rows
    auto derivDot = [&](int b, float& pOut, float& qOut) {
        float p0 = 0.f, p1 = 0.f, q0 = 0.f, q1 = 0.f;
        #pragma unroll
        for (int c = 0; c < 5; ++c) {
            int oct = d_o * 5 + c;
            float4 af = *(const float4*)&act_sh[oct * 128 + ((b ^ oct) & 15) * 8];
            p0 = fdot2f(af.x, st[c].x, p0);     p1 = fdot2f(af.y, st[c].y, p1);
            p0 = fdot2f(af.z, st[c].z, p0);     p1 = fdot2f(af.w, st[c].w, p1);
            q0 = fdot2f(af.x, st[5+c].x, q0);   q1 = fdot2f(af.y, st[5+c].y, q1);
            q0 = fdot2f(af.z, st[5+c].z, q0);   q1 = fdot2f(af.w, st[5+c].w, q1);
        }
        pOut = p0 + p1;
        qOut = q0 + q1;
    };

    phaseA();                   // act(0)
    __syncthreads();

    for (int s = 0; s < NSTEP; ++s) {
        // ---- P1: MFMA(t<512) | deriv(t>=512) + fc5/limb/store(s-1) tail ----
        if (t < 512) {
            v4f c0 = {0.f, 0.f, 0.f, 0.f}, c1 = {0.f, 0.f, 0.f, 0.f};
            #pragma unroll
            for (int ks = 0; ks < 8; ++ks) {
                v8h a  = *(const v8h*)&act_sh[a_off[ks]];
                v8h w0 = __builtin_bit_cast(v8h, st[ks]);
                v8h w1 = __builtin_bit_cast(v8h, st[8 + ks]);
                c0 = __builtin_amdgcn_mfma_f32_16x16x32_f16(a, w0, c0, 0, 0, 0);
                c1 = __builtin_amdgcn_mfma_f32_16x16x32_f16(a, w1, c1, 0, 0, 0);
            }
            *(v4f*)&part[(wv * 2 + 0) * 256 + lidx * 4] = c0;
            *(v4f*)&part[(wv * 2 + 1) * 256 + lidx * 4] = c1;
        } else {
            if (dual) {
                float pA, qA, pB, qB;
                derivDot(d_b,     pA, qA);
                derivDot(d_b + 1, pB, qB);
                float4 osv = *(const float4*)&os_sh[d_o * OS_STR + d_b * 2];
                osv.x += 0.001f * pA;
                osv.y += 0.001f * qA;
                osv.z += 0.001f * pB;
                osv.w += 0.001f * qB;
                *(float4*)&os_sh[d_o * OS_STR + d_b * 2] = osv;
            } else {
                float p, q;
                derivDot(d_b, p, q);
                float2 osv = *(const float2*)&os_sh[d_o * OS_STR + d_b * 2];
                osv.x += 0.001f * p;
                osv.y += 0.001f * q;
                *(float2*)&os_sh[d_o * OS_STR + d_b * 2] = osv;
            }
            if (cb >= 0 && cb < NB && s > 0) {
                // fc5 + limb ODE + stores for step s-1 (b1s from P2 of s-1)
                float a0 = bs0, a1 = bs1;
                #pragma unroll
                for (int i = 0; i < 32; i += 4) {
                    float4 bv = *(const float4*)&b1s[cb * B1STR + i];
                    a0 = dot4(bv, *(const float4*)&fc5_w[i],      a0);
                    a1 = dot4(bv, *(const float4*)&fc5_w[32 + i], a1);
                }
                float f1v = fmaxf(a0, 0.f) * 50.f * fmaxf(l1 - 0.05f, 0.f);
                float f2v = fmaxf(a1, 0.f) * 50.f * fmaxf(l2 - 0.05f, 0.f);
                float domega = (0.02f * (f2v - f1v) - 0.01f * omega) / 0.001f;
                float dl1 = ((0.1f - 0.02f * theta) - l1) / 0.05f;
                float dl2 = ((0.1f + 0.02f * theta) - l2) / 0.05f;
                float pos = fmaf(0.001f, omega,  theta);
                float vel = fmaf(0.001f, domega, omega);
                l1 = fmaf(0.001f, dl1, l1);
                l2 = fmaf(0.001f, dl2, l2);
                bool inb = (pos > -HALF_PI) && (pos < HALF_PI);
                float posc = fminf(fmaxf(pos, -HALF_PI), HALF_PI);
                vel = inb ? vel : 0.f;
                theta = posc;
                omega = vel;
                float4 lo; lo.x = posc; lo.y = vel; lo.z = l1; lo.w = l2;
                *(float4*)&out[((size_t)(s - 1) * BATCH + (b0 + cb)) * 4] = lo;
                float2 ao; ao.x = a0; ao.y = a1;
                *(float2*)&out[ACT_OFF + ((size_t)(s - 1) * BATCH + (b0 + cb)) * 2] = ao;
            }
        }
        __syncthreads();

        // ---- P2: t<512: R (8 partials) -> b1s; all: phaseA(s+1) ----
        if (t < 512) {
            int b = t & 15, j = t >> 4;         // b 0..15, j 0..31
            int g = j >> 4, n = j & 15;
            int Lp = (b >> 2) * 16 + (n ^ ((b >> 2) << 2));   // un-swizzle
            int base = g * 256 + Lp * 4 + (b & 3);
            float sum = 0.f;
            #pragma unroll
            for (int w = 0; w < 8; ++w)
                sum += part[w * 512 + base];
            b1s[b * B1STR + j] = fmaxf(sum + fc4_b[j], 0.f);
        }
        phaseA();
        __syncthreads();
    }

    // ---- tail: fc5 + limb + store for the final step ----
    if (cb >= 0 && cb < NB) {
        const int s = NSTEP - 1;
        float a0 = bs0, a1 = bs1;
        #pragma unroll
        for (int i = 0; i < 32; i += 4) {
            float4 bv = *(const float4*)&b1s[cb * B1STR + i];
            a0 = dot4(bv, *(const float4*)&fc5_w[i],      a0);
            a1 = dot4(bv, *(const float4*)&fc5_w[32 + i], a1);
        }
        float f1v = fmaxf(a0, 0.f) * 50.f * fmaxf(l1 - 0.05f, 0.f);
        float f2v = fmaxf(a1, 0.f) * 50.f * fmaxf(l2 - 0.05f, 0.f);
        float domega = (0.02f * (f2v - f1v) - 0.01f * omega) / 0.001f;
        float dl1 = ((0.1f - 0.02f * theta) - l1) / 0.05f;
        float dl2 = ((0.1f + 0.02f * theta) - l2) / 0.05f;
        float pos = fmaf(0.001f, omega,  theta);
        float vel = fmaf(0.001f, domega, omega);
        l1 = fmaf(0.001f, dl1, l1);
        l2 = fmaf(0.001f, dl2, l2);
        bool inb = (pos > -HALF_PI) && (pos < HALF_PI);
        float posc = fminf(fmaxf(pos, -HALF_PI), HALF_PI);
        vel = inb ? vel : 0.f;
        float4 lo; lo.x = posc; lo.y = vel; lo.z = l1; lo.w = l2;
        *(float4*)&out[((size_t)s * BATCH + (b0 + cb)) * 4] = lo;
        float2 ao; ao.x = a0; ao.y = a1;
        *(float2*)&out[ACT_OFF + ((size_t)s * BATCH + (b0 + cb)) * 2] = ao;
    }
}

extern "C" void kernel_launch(void* const* d_in, const int* in_sizes, int n_in,
                              void* d_out, int out_size, void* d_ws, size_t ws_size,
                              hipStream_t stream) {
    (void)in_sizes; (void)n_in; (void)d_ws; (void)ws_size; (void)out_size;
    const float* x_     = (const float*)d_in[0];
    const float* fc1_w  = (const float*)d_in[1];
    const float* fc1_b  = (const float*)d_in[2];
    const float* fc2_w  = (const float*)d_in[3];
    const float* fc2_b  = (const float*)d_in[4];
    const float* fc3_w  = (const float*)d_in[5];
    const float* fc3_b  = (const float*)d_in[6];
    const float* fcd_w  = (const float*)d_in[7];
    const float* fcd_b  = (const float*)d_in[8];
    const float* enc    = (const float*)d_in[9];
    const float* oscb   = (const float*)d_in[10];
    const float* dec    = (const float*)d_in[11];
    const float* fc4_w  = (const float*)d_in[12];
    const float* fc4_b  = (const float*)d_in[13];
    const float* fc5_w  = (const float*)d_in[14];
    const float* fc5_b  = (const float*)d_in[15];
    float* out = (float*)d_out;

    hipLaunchKernelGGL(prep_f16, dim3(256), dim3(256), 0, stream, fc4_w);
    hipLaunchKernelGGL(net_main, dim3(BATCH / NB), dim3(NTHR), 0, stream,
                       x_, fc1_w, fc1_b, fc2_w, fc2_b, fc3_w, fc3_b,
                       fcd_w, fcd_b, enc, oscb, dec, fc4_b,
                       fc5_w, fc5_b, out);
}

// Round 15
// 1807.233 us; speedup vs baseline: 7.7800x; 1.1041x over previous
//
#include <hip/hip_runtime.h>

#define NTHR 1024
#define NB   16
#define NOSC 50
#define NPER 40
#define KTOT 2000
#define KPAD 2048
#define NSTEP 700
#define BATCH 4096
#define B1STR 36
#define OS_STR 36
#define HALF_PI 1.57079632679489662f
#define ACT_OFF ((size_t)NSTEP * BATCH * 4)

typedef _Float16 v8h __attribute__((ext_vector_type(8)));
typedef _Float16 h2_t __attribute__((ext_vector_type(2)));
typedef float v4f __attribute__((ext_vector_type(4)));

__device__ _Float16 g_w4[32 * KPAD];    // fc4_w in f16, zero-padded K 2000->2048

__device__ __forceinline__ float fdot2f(float a_bits, float b_bits, float acc) {
    h2_t a = __builtin_bit_cast(h2_t, a_bits);
    h2_t b = __builtin_bit_cast(h2_t, b_bits);
#if __has_builtin(__builtin_amdgcn_fdot2)
    return __builtin_amdgcn_fdot2(a, b, acc, false);
#else
    return fmaf((float)a[0], (float)b[0], fmaf((float)a[1], (float)b[1], acc));
#endif
}

__device__ __forceinline__ float dot4(float4 a, float4 b, float acc) {
    acc = fmaf(a.x, b.x, acc);
    acc = fmaf(a.y, b.y, acc);
    acc = fmaf(a.z, b.z, acc);
    acc = fmaf(a.w, b.w, acc);
    return acc;
}

__device__ __forceinline__ float pkrtz(float a, float b) {
    auto q = __builtin_amdgcn_cvt_pkrtz(a, b);
    return __builtin_bit_cast(float, q);
}

// pack 2 f32 -> 2 f16 with round-to-nearest (matches old (_Float16) LDS staging)
__device__ __forceinline__ float cvt2rtn(float a, float b) {
    h2_t u; u[0] = (_Float16)a; u[1] = (_Float16)b;
    return __builtin_bit_cast(float, u);
}

__global__ void prep_f16(const float* __restrict__ fc4_w) {
    int tid = blockIdx.x * blockDim.x + threadIdx.x;   // 65536 total
    int j = tid >> 11, k = tid & 2047;
    g_w4[j * KPAD + k] = (k < KTOT) ? (_Float16)fc4_w[j * KTOT + k] : (_Float16)0.f;
}

// act layout: element (b, k): oct = k>>3, j = k&7, slot = (b ^ oct) & 15
//   f16 idx = oct*128 + slot*8 + j
// r14 post-mortem: LDS pipe ~69% of the 6840-cyc step; P2's critical path is
// R -> phaseA serialized on waves 0-7 while P1's MFMA waves are nearly idle.
// This round: R moves into P1 delayed one step (part[2] double-buffer), fc5
// lags to s-2 (b1s[2]). P2 = pure phaseA on all 16 waves. Arithmetic identical.
// Schedule:
//   P1(s): t<512: MFMA(s)->part[s&1], then R(s-1): part[(s-1)&1]->b1s[(s-1)&1]
//          t>=512: deriv(s); t in [1008,1024): + fc5/limb/store(s-2)
//   P2(s): phaseA(s+1) on all
// Overlaid state st[16]: weights (t<512) OR dec rows (t>=512) -- r14's fix
// for the 128-reg/wave budget (separate arrays spilled, r13).
__global__ __launch_bounds__(NTHR)
void net_main(const float* __restrict__ x,
              const float* __restrict__ fc1_w, const float* __restrict__ fc1_b,
              const float* __restrict__ fc2_w, const float* __restrict__ fc2_b,
              const float* __restrict__ fc3_w, const float* __restrict__ fc3_b,
              const float* __restrict__ fcd_w, const float* __restrict__ fcd_b,
              const float* __restrict__ enc,   const float* __restrict__ osc_bias,
              const float* __restrict__ dec,
              const float* __restrict__ fc4_b,
              const float* __restrict__ fc5_w, const float* __restrict__ fc5_b,
              float* __restrict__ out)
{
    __shared__ __align__(16) _Float16 act_sh[256 * 128];  // 64 KB, frag-major
    __shared__ __align__(16) float part[2 * 4096];        // 32 KB, dbuf MFMA partials
    __shared__ __align__(16) float os_sh[NOSC * OS_STR];  // 7.2 KB [o][b*2+d], padded
    __shared__ __align__(16) float b1s[2][NB * B1STR];    // dbuf
    __shared__ __align__(16) float dir[NB * 2];

    const int t    = threadIdx.x;
    const int lane = t & 63;
    const int wv   = t >> 6;            // 0..15
    const int b0   = blockIdx.x * NB;

    float* h  = (float*)act_sh;         // [NB][128] f32 temp (pre-loop only)
    float* h2 = (float*)act_sh + NB * 128;

    // ---------- precompute: fc1 ----------
    #pragma unroll
    for (int ii = 0; ii < 2; ++ii) {
        int task = t + ii * NTHR;       // 2048 tasks
        int b = task >> 7, i = task & 127;
        float x0 = x[(b0 + b) * 2 + 0];
        float x1 = x[(b0 + b) * 2 + 1];
        float v = fmaf(x0, fc1_w[2 * i], fmaf(x1, fc1_w[2 * i + 1], fc1_b[i]));
        h[b * 128 + i] = fmaxf(v, 0.f);
    }
    __syncthreads();
    // ---------- precompute: fc2 -> h2, fcd -> dir ----------
    #pragma unroll
    for (int ii = 0; ii < 2; ++ii) {
        int task = t + ii * NTHR;
        int b = task >> 7, i = task & 127;
        float acc = fc2_b[i];
        #pragma unroll 4
        for (int k = 0; k < 128; k += 4)
            acc = dot4(*(const float4*)&fc2_w[i * 128 + k],
                       *(const float4*)&h[b * 128 + k], acc);
        h2[b * 128 + i] = fmaxf(acc, 0.f);
    }
    if (t < NB * 2) {
        int b = t >> 1, j = t & 1;
        float acc = fcd_b[j];
        #pragma unroll 4
        for (int k = 0; k < 128; k += 4)
            acc = dot4(*(const float4*)&fcd_w[j * 128 + k],
                       *(const float4*)&h[b * 128 + k], acc);
        dir[b * 2 + j] = acc;
    }
    __syncthreads();
    // ---------- precompute: fc3 -> os_sh ----------
    #pragma unroll
    for (int ii = 0; ii < 2; ++ii) {
        int task = t + ii * NTHR;
        if (task < NOSC * NB * 2) {     // 1600 tasks
            int o = task >> 5, r = task & 31, b = r >> 1;
            int row = o * 2 + (r & 1);
            float acc = fc3_b[row];
            #pragma unroll 4
            for (int k = 0; k < 128; k += 4)
                acc = dot4(*(const float4*)&fc3_w[row * 128 + k],
                           *(const float4*)&h2[b * 128 + k], acc);
            os_sh[o * OS_STR + r] = acc;
        }
    }
    // ---------- enc/bias -> per-thread registers (oct fixed per thread) ----------
    const int my_oct = t >> 2;          // 0..255; threads with oct>=250 idle in phaseA
    float4 e0 = {0,0,0,0}, e1 = {0,0,0,0}, e2 = {0,0,0,0}, e3 = {0,0,0,0};
    float4 bi0 = {0,0,0,0}, bi1 = {0,0,0,0};
    int my_o = 0;
    if (my_oct < 250) {
        const float4* ep = (const float4*)&enc[my_oct * 16];
        e0 = ep[0]; e1 = ep[1]; e2 = ep[2]; e3 = ep[3];
        const float4* bp = (const float4*)&osc_bias[my_oct * 8];
        bi0 = bp[0]; bi1 = bp[1];
        my_o = my_oct / 5;
    }
    // ---------- deriv task mapping (threads t >= 512) ----------
    const int di = t - 512;
    int d_o = 0, d_b = 0;
    bool dual = false;
    if (di >= 0) {
        if (di < 288) { dual = true; d_o = di >> 3; d_b = (di & 7) * 2; }
        else          { int task = di + 288; d_o = task >> 4; d_b = task & 15; }
    }
    // ---------- limb init (threads 1008..1023 own the ODE + stores) ----------
    float theta = 0.f, omega = 0.f, l1 = 0.f, l2 = 0.f, bs0 = 0.f, bs1 = 0.f;
    const int cb = t - 1008;            // 0..15 on tail of wave 15
    if (cb >= 0 && cb < NB) {
        theta = x[(b0 + cb) * 2 + 0];
        l1 = fmaf(-0.02f, theta, 0.1f);
        l2 = fmaf( 0.02f, theta, 0.1f);
    }
    __syncthreads();
    if (cb >= 0 && cb < NB) {
        bs0 = dir[cb * 2 + 0] + fc5_b[0];
        bs1 = dir[cb * 2 + 1] + fc5_b[1];
    }
    // zero act padding (octets 250..255 -> f16 idx [32000, 32768))
    if (t < 768) act_sh[32000 + t] = (_Float16)0.f;

    // ---------- MFMA indices (8 GEMM waves x K=256) ----------
    const int n_col = lane & 15, quad = lane >> 4;
    const int lidx  = lane ^ (quad << 2);           // part write swizzle
    int a_off[8];
    #pragma unroll
    for (int ks = 0; ks < 8; ++ks) {
        int oct = wv * 32 + ks * 4 + quad;          // valid for wv<8
        a_off[ks] = (oct & 255) * 128 + ((n_col ^ (oct & 15)) * 8);
    }

    // ---------- OVERLAID state: st[16] = weights (t<512) OR dec rows (t>=512) ----------
    v4f st[16];
    if (t < 512) {
        const _Float16* wp = &g_w4[n_col * KPAD + wv * 256 + quad * 8];
        #pragma unroll
        for (int ks = 0; ks < 8; ++ks) {
            st[ks]     = __builtin_bit_cast(v4f, *(const v8h*)&wp[ks * 32]);
            st[8 + ks] = __builtin_bit_cast(v4f, *(const v8h*)&wp[16 * KPAD + ks * 32]);
        }
    } else {
        const float* d0p = &dec[(d_o * 2 + 0) * 40];
        const float* d1p = &dec[(d_o * 2 + 1) * 40];
        #pragma unroll
        for (int c = 0; c < 5; ++c) {
            v4f v0, v1;
            v0.x = cvt2rtn(d0p[c*8+0], d0p[c*8+1]);
            v0.y = cvt2rtn(d0p[c*8+2], d0p[c*8+3]);
            v0.z = cvt2rtn(d0p[c*8+4], d0p[c*8+5]);
            v0.w = cvt2rtn(d0p[c*8+6], d0p[c*8+7]);
            v1.x = cvt2rtn(d1p[c*8+0], d1p[c*8+1]);
            v1.y = cvt2rtn(d1p[c*8+2], d1p[c*8+3]);
            v1.z = cvt2rtn(d1p[c*8+4], d1p[c*8+5]);
            v1.w = cvt2rtn(d1p[c*8+6], d1p[c*8+7]);
            st[c]     = v0;
            st[5 + c] = v1;
        }
        #pragma unroll
        for (int i = 10; i < 16; ++i) st[i] = (v4f){0.f, 0.f, 0.f, 0.f};
    }

    // ---------- phase A: act = relu(enc . os + bias), enc/bias in REGISTERS ----------
    auto phaseA = [&]() {
        if (my_oct < 250) {
            const int i4 = (t & 3) << 2;
            float4 osA = *(const float4*)&os_sh[my_o * OS_STR + i4 * 2];      // b=i4+0,1
            float4 osB = *(const float4*)&os_sh[my_o * OS_STR + i4 * 2 + 4];  // b=i4+2,3
            #pragma unroll
            for (int ii = 0; ii < 4; ++ii) {
                int b = i4 + ii;
                float osx = (ii == 0) ? osA.x : (ii == 1) ? osA.z : (ii == 2) ? osB.x : osB.z;
                float osy = (ii == 0) ? osA.y : (ii == 1) ? osA.w : (ii == 2) ? osB.y : osB.w;
                float r0 = fmaxf(fmaf(e0.x, osx, fmaf(e0.y, osy, bi0.x)), 0.f);
                float r1 = fmaxf(fmaf(e0.z, osx, fmaf(e0.w, osy, bi0.y)), 0.f);
                float r2 = fmaxf(fmaf(e1.x, osx, fmaf(e1.y, osy, bi0.z)), 0.f);
                float r3 = fmaxf(fmaf(e1.z, osx, fmaf(e1.w, osy, bi0.w)), 0.f);
                float r4 = fmaxf(fmaf(e2.x, osx, fmaf(e2.y, osy, bi1.x)), 0.f);
                float r5 = fmaxf(fmaf(e2.z, osx, fmaf(e2.w, osy, bi1.y)), 0.f);
                float r6 = fmaxf(fmaf(e3.x, osx, fmaf(e3.y, osy, bi1.z)), 0.f);
                float r7 = fmaxf(fmaf(e3.z, osx, fmaf(e3.w, osy, bi1.w)), 0.f);
                float4 pk;
                pk.x = pkrtz(r0, r1);
                pk.y = pkrtz(r2, r3);
                pk.z = pkrtz(r4, r5);
                pk.w = pkrtz(r6, r7);
                *(float4*)&act_sh[my_oct * 128 + ((b ^ my_oct) & 15) * 8] = pk;
            }
        }
    };

    // deriv dot for one b using st[0..9] as dec rows
    auto derivDot = [&](int b, float& pOut, float& qOut) {
        float p0 = 0.f, p1 = 0.f, q0 = 0.f, q1 = 0.f;
        #pragma unroll
        for (int c = 0; c < 5; ++c) {
            int oct = d_o * 5 + c;
            float4 af = *(const float4*)&act_sh[oct * 128 + ((b ^ oct) & 15) * 8];
            p0 = fdot2f(af.x, st[c].x, p0);     p1 = fdot2f(af.y, st[c].y, p1);
            p0 = fdot2f(af.z, st[c].z, p0);     p1 = fdot2f(af.w, st[c].w, p1);
            q0 = fdot2f(af.x, st[5+c].x, q0);   q1 = fdot2f(af.y, st[5+c].y, q1);
            q0 = fdot2f(af.z, st[5+c].z, q0);   q1 = fdot2f(af.w, st[5+c].w, q1);
        }
        pOut = p0 + p1;
        qOut = q0 + q1;
    };

    // fc5 + limb ODE + stores for step sm (cb threads only; b1s buffer sm&1)
    auto fc5Limb = [&](int sm) {
        float a0 = bs0, a1 = bs1;
        #pragma unroll
        for (int i = 0; i < 32; i += 4) {
            float4 bv = *(const float4*)&b1s[sm & 1][cb * B1STR + i];
            a0 = dot4(bv, *(const float4*)&fc5_w[i],      a0);
            a1 = dot4(bv, *(const float4*)&fc5_w[32 + i], a1);
        }
        float f1v = fmaxf(a0, 0.f) * 50.f * fmaxf(l1 - 0.05f, 0.f);
        float f2v = fmaxf(a1, 0.f) * 50.f * fmaxf(l2 - 0.05f, 0.f);
        float domega = (0.02f * (f2v - f1v) - 0.01f * omega) / 0.001f;
        float dl1 = ((0.1f - 0.02f * theta) - l1) / 0.05f;
        float dl2 = ((0.1f + 0.02f * theta) - l2) / 0.05f;
        float pos = fmaf(0.001f, omega,  theta);
        float vel = fmaf(0.001f, domega, omega);
        l1 = fmaf(0.001f, dl1, l1);
        l2 = fmaf(0.001f, dl2, l2);
        bool inb = (pos > -HALF_PI) && (pos < HALF_PI);
        float posc = fminf(fmaxf(pos, -HALF_PI), HALF_PI);
        vel = inb ? vel : 0.f;
        theta = posc;
        omega = vel;
        float4 lo; lo.x = posc; lo.y = vel; lo.z = l1; lo.w = l2;
        *(float4*)&out[((size_t)sm * BATCH + (b0 + cb)) * 4] = lo;
        float2 ao; ao.x = a0; ao.y = a1;
        *(float2*)&out[ACT_OFF + ((size_t)sm * BATCH + (b0 + cb)) * 2] = ao;
    };

    phaseA();                   // act(0)
    __syncthreads();

    for (int s = 0; s < NSTEP; ++s) {
        // ---- P1: t<512: MFMA(s)->part[s&1], then R(s-1) | t>=512: deriv(s) (+fc5(s-2)) ----
        if (t < 512) {
            const int pb = (s & 1) * 4096;
            v4f c0 = {0.f, 0.f, 0.f, 0.f}, c1 = {0.f, 0.f, 0.f, 0.f};
            #pragma unroll
            for (int ks = 0; ks < 8; ++ks) {
                v8h a  = *(const v8h*)&act_sh[a_off[ks]];
                v8h w0 = __builtin_bit_cast(v8h, st[ks]);
                v8h w1 = __builtin_bit_cast(v8h, st[8 + ks]);
                c0 = __builtin_amdgcn_mfma_f32_16x16x32_f16(a, w0, c0, 0, 0, 0);
                c1 = __builtin_amdgcn_mfma_f32_16x16x32_f16(a, w1, c1, 0, 0, 0);
            }
            *(v4f*)&part[pb + (wv * 2 + 0) * 256 + lidx * 4] = c0;
            *(v4f*)&part[pb + (wv * 2 + 1) * 256 + lidx * 4] = c1;
            if (s > 0) {                // R(s-1) from part[(s-1)&1]
                const int pr = ((s - 1) & 1) * 4096;
                int b = t & 15, j = t >> 4;         // b 0..15, j 0..31
                int g = j >> 4, n = j & 15;
                int Lp = (b >> 2) * 16 + (n ^ ((b >> 2) << 2));
                int base = pr + g * 256 + Lp * 4 + (b & 3);
                float sum = 0.f;
                #pragma unroll
                for (int w = 0; w < 8; ++w)
                    sum += part[w * 512 + base];
                b1s[(s - 1) & 1][b * B1STR + j] = fmaxf(sum + fc4_b[j], 0.f);
            }
        } else {
            if (dual) {
                float pA, qA, pB, qB;
                derivDot(d_b,     pA, qA);
                derivDot(d_b + 1, pB, qB);
                float4 osv = *(const float4*)&os_sh[d_o * OS_STR + d_b * 2];
                osv.x += 0.001f * pA;
                osv.y += 0.001f * qA;
                osv.z += 0.001f * pB;
                osv.w += 0.001f * qB;
                *(float4*)&os_sh[d_o * OS_STR + d_b * 2] = osv;
            } else {
                float p, q;
                derivDot(d_b, p, q);
                float2 osv = *(const float2*)&os_sh[d_o * OS_STR + d_b * 2];
                osv.x += 0.001f * p;
                osv.y += 0.001f * q;
                *(float2*)&os_sh[d_o * OS_STR + d_b * 2] = osv;
            }
            if (cb >= 0 && cb < NB && s >= 2)
                fc5Limb(s - 2);
        }
        __syncthreads();

        // ---- P2: phaseA(s+1) on all waves ----
        phaseA();
        __syncthreads();
    }

    // ---- tail: R(699) + fc5(698), then fc5(699) ----
    if (t < 512) {
        const int pr = ((NSTEP - 1) & 1) * 4096;
        int b = t & 15, j = t >> 4;
        int g = j >> 4, n = j & 15;
        int Lp = (b >> 2) * 16 + (n ^ ((b >> 2) << 2));
        int base = pr + g * 256 + Lp * 4 + (b & 3);
        float sum = 0.f;
        #pragma unroll
        for (int w = 0; w < 8; ++w)
            sum += part[w * 512 + base];
        b1s[(NSTEP - 1) & 1][b * B1STR + j] = fmaxf(sum + fc4_b[j], 0.f);
    } else if (cb >= 0 && cb < NB) {
        fc5Limb(NSTEP - 2);
    }
    __syncthreads();
    if (cb >= 0 && cb < NB)
        fc5Limb(NSTEP - 1);
}

extern "C" void kernel_launch(void* const* d_in, const int* in_sizes, int n_in,
                              void* d_out, int out_size, void* d_ws, size_t ws_size,
                              hipStream_t stream) {
    (void)in_sizes; (void)n_in; (void)d_ws; (void)ws_size; (void)out_size;
    const float* x_     = (const float*)d_in[0];
    const float* fc1_w  = (const float*)d_in[1];
    const float* fc1_b  = (const float*)d_in[2];
    const float* fc2_w  = (const float*)d_in[3];
    const float* fc2_b  = (const float*)d_in[4];
    const float* fc3_w  = (const float*)d_in[5];
    const float* fc3_b  = (const float*)d_in[6];
    const float* fcd_w  = (const float*)d_in[7];
    const float* fcd_b  = (const float*)d_in[8];
    const float* enc    = (const float*)d_in[9];
    const float* oscb   = (const float*)d_in[10];
    const float* dec    = (const float*)d_in[11];
    const float* fc4_w  = (const float*)d_in[12];
    const float* fc4_b  = (const float*)d_in[13];
    const float* fc5_w  = (const float*)d_in[14];
    const float* fc5_b  = (const float*)d_in[15];
    float* out = (float*)d_out;

    hipLaunchKernelGGL(prep_f16, dim3(256), dim3(256), 0, stream, fc4_w);
    hipLaunchKernelGGL(net_main, dim3(BATCH / NB), dim3(NTHR), 0, stream,
                       x_, fc1_w, fc1_b, fc2_w, fc2_b, fc3_w, fc3_b,
                       fcd_w, fcd_b, enc, oscb, dec, fc4_b,
                       fc5_w, fc5_b, out);
}